// Round 1
// baseline (1516.818 us; speedup 1.0000x reference)
//
#include <hip/hip_runtime.h>
#include <cstdint>
#include <cstddef>

#define T_LEN 8192
#define BATCH 64
#define HID   10
#define CH    66
#define EEG   64
#define CHUNK 512
#define WARM  32

// ---------------------------------------------------------------------------
// K1: front projection   y[b][t][h] = b_front[h] + sum_c x[b,0,c+1,t]*w_front[h,c]
// grid (32, 64), block 256. Coalesced x reads (lane = t).
// ---------------------------------------------------------------------------
__global__ void k_front(const float* __restrict__ x, const float* __restrict__ wf_g,
                        const float* __restrict__ bf_g, float* __restrict__ y) {
    __shared__ float wf[EEG][HID];   // wf[c][h]
    __shared__ float bf[HID];
    int tid = threadIdx.x;
    for (int i = tid; i < EEG * HID; i += 256) {
        int h = i / EEG, c = i % EEG;      // w_front layout (H, C)
        wf[c][h] = wf_g[i];
    }
    if (tid < HID) bf[tid] = bf_g[tid];
    __syncthreads();

    int b = blockIdx.y;
    int t = blockIdx.x * 256 + tid;
    const float* xb = x + ((size_t)b * CH + 1) * T_LEN + t;   // skip aud channel 0
    float acc[HID];
#pragma unroll
    for (int h = 0; h < HID; ++h) acc[h] = bf[h];
#pragma unroll 4
    for (int c = 0; c < EEG; ++c) {
        float xv = xb[(size_t)c * T_LEN];
#pragma unroll
        for (int h = 0; h < HID; ++h) acc[h] = fmaf(xv, wf[c][h], acc[h]);
    }
    float* yo = y + ((size_t)b * T_LEN + t) * HID;
#pragma unroll
    for (int h = 0; h < HID; ++h) yo[h] = acc[h];
}

// ---------------------------------------------------------------------------
// K2: front LIF, chunk-parallel over t (decay 0.25 -> 32-step warmup is exact
// to ~5e-20). Packs 10 spike bits per (b,t) into u16 via ballot.
// grid 256 (= 16 chunks x 16 batch-quads), block 64 (4 groups of 16 lanes).
// ---------------------------------------------------------------------------
__global__ void k_flif(const float* __restrict__ y, unsigned short* __restrict__ smask) {
    int c    = blockIdx.x >> 4;      // chunk 0..15
    int bq   = blockIdx.x & 15;      // batch quad
    int lane = threadIdx.x;
    int g = lane >> 4, h = lane & 15;
    int b = bq * 4 + g;
    bool act = (h < HID);
    const float* yb = y + (size_t)b * T_LEN * HID + h;
    int t0 = c * CHUNK;
    int ts = t0 - WARM; if (ts < 0) ts = 0;
    float u = 0.f, o = 0.f;
    for (int t = ts; t < t0 + CHUNK; ++t) {
        float yv = act ? yb[(size_t)t * HID] : -1.0f;
        u = (o > 0.5f) ? yv : fmaf(0.25f, u, yv);   // 0.25*u exact -> fma == ref
        bool sp = (u > 0.2f);                        // u - VTH > 0  <=>  u > VTH
        o = sp ? 1.0f : 0.0f;
        unsigned long long bal = __ballot(sp);
        if (t >= t0 && h == 0) {
            smask[(size_t)b * T_LEN + t] =
                (unsigned short)((bal >> (g * 16)) & 0x3FFull);
        }
    }
}

// ---------------------------------------------------------------------------
// K3: LSNN recurrent scan + classifier LIF + mean.  1 wave per batch.
// Lanes 0..9: hidden units. Lanes 10..11: classifier units.
// LDS table T[mask][r]: r<10 -> dot(mask, w_in[r]); r>=10 -> dot(mask, w_cls[r-10]).
// x_in lookups prefetched 1 block (8 iters) ahead; classifier consumes zmask
// lookups 1 block late (software pipeline). Only the rec dot is on the chain.
// Note: b_dec == VTH exactly (b0 = VTH, BETA = 0) -> threshold is constant 0.2.
// ---------------------------------------------------------------------------
#define LOOKUP8(m, X)                                                     \
    do {                                                                  \
        unsigned w0 = (m).x, w1 = (m).y, w2 = (m).z, w3 = (m).w;          \
        X[0] = T[(w0 & 0xFFFFu) * 12 + r]; X[1] = T[(w0 >> 16) * 12 + r]; \
        X[2] = T[(w1 & 0xFFFFu) * 12 + r]; X[3] = T[(w1 >> 16) * 12 + r]; \
        X[4] = T[(w2 & 0xFFFFu) * 12 + r]; X[5] = T[(w2 >> 16) * 12 + r]; \
        X[6] = T[(w3 & 0xFFFFu) * 12 + r]; X[7] = T[(w3 >> 16) * 12 + r]; \
    } while (0)

__global__ __launch_bounds__(64) void k_lsnn(
    const unsigned short* __restrict__ smask,
    const float* __restrict__ w_in, const float* __restrict__ w_rec,
    const float* __restrict__ w_cls, const float* __restrict__ b_cls,
    float* __restrict__ out) {
    __shared__ float T[1024 * 12];
    int lane = threadIdx.x;
    int b = blockIdx.x;
    int q = lane / 12, r = lane % 12;

    // --- build subset-sum table (levels over bits; 5 q-groups split the m range;
    //     q==5 lanes duplicate q==0 entries harmlessly) ---
    float wt[HID];
#pragma unroll
    for (int j = 0; j < HID; ++j)
        wt[j] = (r < HID) ? w_in[r * HID + j] : w_cls[(r - HID) * HID + j];

    if (q == 0) T[r] = 0.f;
    __syncthreads();
#pragma unroll
    for (int j = 0; j < HID; ++j) {
        int lim = 1 << j;
        for (int m = q; m < lim; m += 5)
            T[(m | lim) * 12 + r] = T[m * 12 + r] + wt[j];
        __syncthreads();
    }

    float wb[HID];
#pragma unroll
    for (int j = 0; j < HID; ++j)
        wb[j] = (lane < HID) ? w_rec[lane * HID + j] : 0.f;
    float bcl = (r >= HID) ? b_cls[r - HID] : 0.f;

    const unsigned short* sm = smask + (size_t)b * T_LEN;

    // prologue: masks for blocks 0 and 1; x_in lookups for block 0
    uint4 m0 = *(const uint4*)(sm);
    uint4 mB = *(const uint4*)(sm + 8);
    float Xc[8], Xn[8], Cc[8], Cn[8];
    LOOKUP8(m0, Xc);
#pragma unroll
    for (int u = 0; u < 8; ++u) Cc[u] = 0.f;

    float v = 0.f, cur = 0.f;
    unsigned zmask = 0;
    float uc = 0.f, oc = 0.f, accs = 0.f;

    for (int blk = 0; blk < 1024; ++blk) {
        int nb = blk + 2; if (nb > 1023) nb = 1023;
        uint4 mF = *(const uint4*)(sm + (size_t)nb * 8);
        LOOKUP8(mB, Xn);   // prefetch x_in for next block (off-chain)
#pragma unroll
        for (int u = 0; u < 8; ++u) {
            // recurrent masked dot (critical chain), tree-shaped
            float s0 = ((zmask & 1u)   ? wb[0] : 0.f) + ((zmask & 2u)   ? wb[1] : 0.f);
            float s1 = ((zmask & 4u)   ? wb[2] : 0.f) + ((zmask & 8u)   ? wb[3] : 0.f);
            float s2 = ((zmask & 16u)  ? wb[4] : 0.f) + ((zmask & 32u)  ? wb[5] : 0.f);
            float s3 = ((zmask & 64u)  ? wb[6] : 0.f) + ((zmask & 128u) ? wb[7] : 0.f);
            float s4 = ((zmask & 256u) ? wb[8] : 0.f) + ((zmask & 512u) ? wb[9] : 0.f);
            float rec = ((s0 + s1) + (s2 + s3)) + s4;

            float ij = (cur + Xc[u]) + rec;
            float vd = v + 0.1f * (ij - v);
            cur = ij - 0.2f * ij;
            bool zb = vd > 0.2f;              // v_dec - b_dec > 0, b_dec == 0.2
            unsigned long long bal = __ballot(zb);
            v = zb ? 0.f : vd;                // cndmask off the ballot bits
            zmask = (unsigned)bal & 0x3FFu;
            Cn[u] = T[zmask * 12 + r];        // classifier lookup, consumed next blk
        }
        if (blk) {
#pragma unroll
            for (int u = 0; u < 8; ++u) {     // classifier LIF for block blk-1
                float ci = Cc[u] + bcl;
                uc = (oc > 0.5f) ? ci : fmaf(0.25f, uc, ci);
                bool so = uc > 0.2f;
                oc = so ? 1.f : 0.f;
                accs += oc;
            }
        }
#pragma unroll
        for (int u = 0; u < 8; ++u) { Xc[u] = Xn[u]; Cc[u] = Cn[u]; }
        mB = mF;
    }
    // epilogue: classifier for the last block
#pragma unroll
    for (int u = 0; u < 8; ++u) {
        float ci = Cc[u] + bcl;
        uc = (oc > 0.5f) ? ci : fmaf(0.25f, uc, ci);
        bool so = uc > 0.2f;
        oc = so ? 1.f : 0.f;
        accs += oc;
    }
    if (lane == 10 || lane == 11)
        out[b * 2 + (lane - 10)] = accs * (1.0f / 8192.0f);
}

// ---------------------------------------------------------------------------
extern "C" void kernel_launch(void* const* d_in, const int* in_sizes, int n_in,
                              void* d_out, int out_size, void* d_ws, size_t ws_size,
                              hipStream_t stream) {
    const float* x       = (const float*)d_in[0];
    const float* w_front = (const float*)d_in[1];
    const float* b_front = (const float*)d_in[2];
    const float* w_in    = (const float*)d_in[3];
    const float* w_rec   = (const float*)d_in[4];
    const float* w_cls   = (const float*)d_in[5];
    const float* b_cls   = (const float*)d_in[6];
    float* out = (float*)d_out;

    float* y = (float*)d_ws;                                   // 64*8192*10*4 = 20 MB
    unsigned short* smask =
        (unsigned short*)((char*)d_ws + (size_t)BATCH * T_LEN * HID * sizeof(float));

    k_front<<<dim3(T_LEN / 256, BATCH), 256, 0, stream>>>(x, w_front, b_front, y);
    k_flif<<<dim3(256), 64, 0, stream>>>(y, smask);
    k_lsnn<<<dim3(BATCH), 64, 0, stream>>>(smask, w_in, w_rec, w_cls, b_cls, out);
}

// Round 2
// 383.104 us; speedup vs baseline: 3.9593x; 3.9593x over previous
//
#include <hip/hip_runtime.h>
#include <cstdint>
#include <cstddef>

#define T_LEN 8192
#define BATCH 64
#define HID   10
#define CH    66
#define EEG   64

// ---------------------------------------------------------------------------
// K1: front projection  y[b][t][h] = b_front[h] + sum_c x[b,0,c+1,t]*w_front[h,c]
// grid (8, 64), block 256, 4 t per thread (float4 loads, 1 KB/wave-instr).
// ---------------------------------------------------------------------------
__global__ void k_front(const float* __restrict__ x, const float* __restrict__ wf_g,
                        const float* __restrict__ bf_g, float* __restrict__ y) {
    __shared__ float wf[EEG][HID];   // wf[c][h]
    __shared__ float bf[HID];
    int tid = threadIdx.x;
    for (int i = tid; i < EEG * HID; i += 256) {
        int h = i / EEG, c = i % EEG;      // w_front layout (H, C)
        wf[c][h] = wf_g[i];
    }
    if (tid < HID) bf[tid] = bf_g[tid];
    __syncthreads();

    int b = blockIdx.y;
    int t4 = (blockIdx.x * 256 + tid) * 4;
    const float* xb = x + ((size_t)b * CH + 1) * T_LEN + t4;   // skip aud channel 0
    float acc[4][HID];
#pragma unroll
    for (int j = 0; j < 4; ++j)
#pragma unroll
        for (int h = 0; h < HID; ++h) acc[j][h] = bf[h];
#pragma unroll 4
    for (int c = 0; c < EEG; ++c) {
        float4 xv = *(const float4*)(xb + (size_t)c * T_LEN);
#pragma unroll
        for (int h = 0; h < HID; ++h) {
            float w = wf[c][h];
            acc[0][h] = fmaf(xv.x, w, acc[0][h]);
            acc[1][h] = fmaf(xv.y, w, acc[1][h]);
            acc[2][h] = fmaf(xv.z, w, acc[2][h]);
            acc[3][h] = fmaf(xv.w, w, acc[3][h]);
        }
    }
    float* yo = y + ((size_t)b * T_LEN + t4) * HID;   // 40 contiguous floats
    float vals[40];
#pragma unroll
    for (int j = 0; j < 4; ++j)
#pragma unroll
        for (int h = 0; h < HID; ++h) vals[j * HID + h] = acc[j][h];
#pragma unroll
    for (int k = 0; k < 10; ++k)
        ((float4*)yo)[k] = make_float4(vals[4*k], vals[4*k+1], vals[4*k+2], vals[4*k+3]);
}

// ---------------------------------------------------------------------------
// K2: front LIF, 32 chunks of 256 steps, warm 32 (exact to 0.25^32 ~ 5e-20).
// grid 512 (= 32 chunks x 16 batch-quads), block 64 (4 groups of 16 lanes).
// Groups of 8 steps with 2-deep load prefetch to hide global latency.
// ---------------------------------------------------------------------------
__global__ __launch_bounds__(64) void k_flif(const float* __restrict__ y,
                                             unsigned short* __restrict__ smask) {
    int c    = blockIdx.x >> 4;      // chunk 0..31
    int bq   = blockIdx.x & 15;      // batch quad
    int lane = threadIdx.x;
    int g = lane >> 4, h = lane & 15;
    int b = bq * 4 + g;
    bool act = (h < HID);
    const float* yb = y + (size_t)b * T_LEN * HID + h;
    int t0 = c * 256;
    int ts = t0 - 32; if (ts < 0) ts = 0;
    int ng = (t0 + 256 - ts) >> 3;

    float bufA[8], bufB[8], bufC[8];
    auto LD = [&](float* dst, int grp) {
        int gg = grp < ng ? grp : ng - 1;
        int tb = ts + gg * 8;
#pragma unroll
        for (int k = 0; k < 8; ++k)
            dst[k] = act ? yb[(size_t)(tb + k) * HID] : -1.0f;
    };
    LD(bufA, 0); LD(bufB, 1);

    float u = 0.f, o = 0.f;
    for (int gr = 0; gr < ng; ++gr) {
        LD(bufC, gr + 2);
        int tb = ts + gr * 8;
#pragma unroll
        for (int k = 0; k < 8; ++k) {
            float yv = bufA[k];
            u = (o > 0.5f) ? yv : fmaf(0.25f, u, yv);   // 0.25*u exact -> matches ref
            bool sp = (u > 0.2f);
            o = sp ? 1.0f : 0.0f;
            unsigned long long bal = __ballot(sp);
            int t = tb + k;
            if (t >= t0 && h == 0)
                smask[(size_t)b * T_LEN + t] =
                    (unsigned short)((bal >> (g * 16)) & 0x3FFull);
        }
#pragma unroll
        for (int k = 0; k < 8; ++k) { bufA[k] = bufB[k]; bufB[k] = bufC[k]; }
    }
}

// ---------------------------------------------------------------------------
// K3: LSNN scan + classifier, 32 chunks of 256 steps, warm 256.
// State contracts (i x0.8, v x0.9 + resets, b == VTH exactly) so zero-start +
// 256 warmup reproduces state to ~1e-12; spike flips cost 1.2e-4 vs 1.5e-2 tol.
// Block = 256 thr = 4 waves, each wave one chunk; grid = 64 b x 8 = 512.
// Split subset-sum tables: dot(mask, w) = T[lo5][r] + T[32+hi5][r]; 3 KB LDS.
// x_in lookups prefetched 1 group (8 iters) ahead; classifier lookups consumed
// 1 group late. Only the 10-term rec dot stays on the sequential chain.
// ---------------------------------------------------------------------------
#define XLOOK(mv, X)                                                        \
    do {                                                                    \
        unsigned mm[8] = { (mv).x & 0xFFFFu, (mv).x >> 16,                  \
                           (mv).y & 0xFFFFu, (mv).y >> 16,                  \
                           (mv).z & 0xFFFFu, (mv).z >> 16,                  \
                           (mv).w & 0xFFFFu, (mv).w >> 16 };                \
        _Pragma("unroll")                                                   \
        for (int uu = 0; uu < 8; ++uu)                                      \
            X[uu] = T[(mm[uu] & 31u) * 12 + r] +                            \
                    T[(32u + (mm[uu] >> 5)) * 12 + r];                      \
    } while (0)

__global__ __launch_bounds__(256) void k_lsnn(
    const unsigned short* __restrict__ smask,
    const float* __restrict__ w_in, const float* __restrict__ w_rec,
    const float* __restrict__ w_cls, const float* __restrict__ b_cls,
    float* __restrict__ out) {
    __shared__ float T[768];    // [hi?32+m5][12]
    int tid = threadIdx.x;
    for (int i = tid; i < 768; i += 256) {
        int r2 = i % 12;
        int m  = (i / 12) & 31;
        int hi = i / (12 * 32);
        const float* wrow = (r2 < HID) ? (w_in + r2 * HID) : (w_cls + (r2 - HID) * HID);
        float s = 0.f;
#pragma unroll
        for (int j = 0; j < 5; ++j)
            if (m & (1u << j)) s += wrow[hi * 5 + j];
        T[i] = s;
    }
    __syncthreads();

    int lane = tid & 63, w = tid >> 6;
    int b = blockIdx.x >> 3, cg = blockIdx.x & 7;
    int chunk = cg * 4 + w;
    int t0 = chunk * 256;
    int ts = t0 - 256; if (ts < 0) ts = 0;
    int ng = (t0 + 256 - ts) >> 3;
    int r = lane % 12;

    float wb[HID];
#pragma unroll
    for (int j = 0; j < HID; ++j)
        wb[j] = (lane < HID) ? w_rec[lane * HID + j] : 0.f;
    float bcl = (r >= HID) ? b_cls[r - HID] : 0.f;

    const unsigned short* sm = smask + (size_t)b * T_LEN + ts;

    uint4 mcur = *(const uint4*)(sm);
    uint4 mnext = *(const uint4*)(sm + (ng > 1 ? 8 : 0));
    float Xc[8], Xn[8], CLo[8], CHi[8], PLo[8], PHi[8];
    XLOOK(mcur, Xc);
#pragma unroll
    for (int u = 0; u < 8; ++u) { PLo[u] = 0.f; PHi[u] = 0.f; }

    float v = 0.f, vmul = 0.f, cur = 0.f;
    unsigned zmask = 0;
    float uc = 0.f, oc = 0.f, accs = 0.f;

    for (int gr = 0; gr < ng; ++gr) {
        int nb = gr + 2; if (nb > ng - 1) nb = ng - 1;
        uint4 mfar = *(const uint4*)(sm + (size_t)nb * 8);
        XLOOK(mnext, Xn);   // x_in for next group (off-chain)
#pragma unroll
        for (int u = 0; u < 8; ++u) {
            float s0 = ((zmask & 1u)   ? wb[0] : 0.f) + ((zmask & 2u)   ? wb[1] : 0.f);
            float s1 = ((zmask & 4u)   ? wb[2] : 0.f) + ((zmask & 8u)   ? wb[3] : 0.f);
            float s2 = ((zmask & 16u)  ? wb[4] : 0.f) + ((zmask & 32u)  ? wb[5] : 0.f);
            float s3 = ((zmask & 64u)  ? wb[6] : 0.f) + ((zmask & 128u) ? wb[7] : 0.f);
            float s4 = ((zmask & 256u) ? wb[8] : 0.f) + ((zmask & 512u) ? wb[9] : 0.f);
            float rec = ((s0 + s1) + (s2 + s3)) + s4;

            float ij = (cur + Xc[u]) + rec;
            float vd = fmaf(0.1f, ij, vmul);     // v + 0.1*(ij - v)
            cur = fmaf(-0.2f, ij, ij);           // ij - 0.2*ij
            bool zb = vd > 0.2f;                 // b_dec == VTH exactly
            unsigned long long bal = __ballot(zb);
            v = zb ? 0.f : vd;
            vmul = 0.9f * v;                     // off-chain for next iter
            zmask = (unsigned)bal & 0x3FFu;
            CLo[u] = T[(zmask & 31u) * 12 + r];  // classifier lookup, consumed next grp
            CHi[u] = T[(32u + (zmask >> 5)) * 12 + r];
        }
        if (gr) {
            bool in = (ts + 8 * (gr - 1)) >= t0;
#pragma unroll
            for (int u = 0; u < 8; ++u) {
                float ci = (PLo[u] + PHi[u]) + bcl;
                uc = (oc > 0.5f) ? ci : fmaf(0.25f, uc, ci);
                oc = (uc > 0.2f) ? 1.f : 0.f;
                if (in) accs += oc;
            }
        }
#pragma unroll
        for (int u = 0; u < 8; ++u) { Xc[u] = Xn[u]; PLo[u] = CLo[u]; PHi[u] = CHi[u]; }
        mcur = mnext; mnext = mfar;
    }
    // epilogue: classifier for the last group (always in-chunk)
#pragma unroll
    for (int u = 0; u < 8; ++u) {
        float ci = (PLo[u] + PHi[u]) + bcl;
        uc = (oc > 0.5f) ? ci : fmaf(0.25f, uc, ci);
        oc = (uc > 0.2f) ? 1.f : 0.f;
        accs += oc;
    }
    if (lane == 10 || lane == 11)
        atomicAdd(&out[b * 2 + (lane - 10)], accs * (1.0f / 8192.0f));
}

// ---------------------------------------------------------------------------
extern "C" void kernel_launch(void* const* d_in, const int* in_sizes, int n_in,
                              void* d_out, int out_size, void* d_ws, size_t ws_size,
                              hipStream_t stream) {
    const float* x       = (const float*)d_in[0];
    const float* w_front = (const float*)d_in[1];
    const float* b_front = (const float*)d_in[2];
    const float* w_in    = (const float*)d_in[3];
    const float* w_rec   = (const float*)d_in[4];
    const float* w_cls   = (const float*)d_in[5];
    const float* b_cls   = (const float*)d_in[6];
    float* out = (float*)d_out;

    float* y = (float*)d_ws;                                   // 64*8192*10*4 = 20 MB
    unsigned short* smask =
        (unsigned short*)((char*)d_ws + (size_t)BATCH * T_LEN * HID * sizeof(float));

    hipMemsetAsync(out, 0, (size_t)out_size * sizeof(float), stream);
    k_front<<<dim3(T_LEN / 1024, BATCH), 256, 0, stream>>>(x, w_front, b_front, y);
    k_flif<<<dim3(512), 64, 0, stream>>>(y, smask);
    k_lsnn<<<dim3(512), 256, 0, stream>>>(smask, w_in, w_rec, w_cls, b_cls, out);
}

// Round 4
// 319.848 us; speedup vs baseline: 4.7423x; 1.1978x over previous
//
#include <hip/hip_runtime.h>
#include <cstdint>
#include <cstddef>

#define T_LEN 8192
#define BATCH 64
#define HID   10
#define CH    66
#define EEG   64
#define SM_STRIDE 8320   // 128-entry zero pad + 8192 live, per batch

// ---------------------------------------------------------------------------
// K1: front projection  y[b][t][h] = b_front[h] + sum_c x[b,0,c+1,t]*w_front[h,c]
// grid (8, 64), block 256, 4 t per thread (float4 loads).
// ---------------------------------------------------------------------------
__global__ void k_front(const float* __restrict__ x, const float* __restrict__ wf_g,
                        const float* __restrict__ bf_g, float* __restrict__ y) {
    __shared__ float wf[EEG][HID];   // wf[c][h]
    __shared__ float bf[HID];
    int tid = threadIdx.x;
    for (int i = tid; i < EEG * HID; i += 256) {
        int h = i / EEG, c = i % EEG;      // w_front layout (H, C)
        wf[c][h] = wf_g[i];
    }
    if (tid < HID) bf[tid] = bf_g[tid];
    __syncthreads();

    int b = blockIdx.y;
    int t4 = (blockIdx.x * 256 + tid) * 4;
    const float* xb = x + ((size_t)b * CH + 1) * T_LEN + t4;   // skip aud channel 0
    float acc[4][HID];
#pragma unroll
    for (int j = 0; j < 4; ++j)
#pragma unroll
        for (int h = 0; h < HID; ++h) acc[j][h] = bf[h];
#pragma unroll 4
    for (int c = 0; c < EEG; ++c) {
        float4 xv = *(const float4*)(xb + (size_t)c * T_LEN);
#pragma unroll
        for (int h = 0; h < HID; ++h) {
            float w = wf[c][h];
            acc[0][h] = fmaf(xv.x, w, acc[0][h]);
            acc[1][h] = fmaf(xv.y, w, acc[1][h]);
            acc[2][h] = fmaf(xv.z, w, acc[2][h]);
            acc[3][h] = fmaf(xv.w, w, acc[3][h]);
        }
    }
    float* yo = y + ((size_t)b * T_LEN + t4) * HID;   // 40 contiguous floats
    float vals[40];
#pragma unroll
    for (int j = 0; j < 4; ++j)
#pragma unroll
        for (int h = 0; h < HID; ++h) vals[j * HID + h] = acc[j][h];
#pragma unroll
    for (int k = 0; k < 10; ++k)
        ((float4*)yo)[k] = make_float4(vals[4*k], vals[4*k+1], vals[4*k+2], vals[4*k+3]);
}

// ---------------------------------------------------------------------------
// K2: front LIF, 32 chunks of 256 steps, warm 32 (exact to 0.25^32 ~ 5e-20).
// grid 512 (= 32 chunks x 16 batch-quads), block 64 (4 groups of 16 lanes).
// Writes 10-bit spike masks into the PADDED smask layout (offset +128).
// ---------------------------------------------------------------------------
__global__ __launch_bounds__(64) void k_flif(const float* __restrict__ y,
                                             unsigned short* __restrict__ smask) {
    int c    = blockIdx.x >> 4;      // chunk 0..31
    int bq   = blockIdx.x & 15;      // batch quad
    int lane = threadIdx.x;
    int g = lane >> 4, h = lane & 15;
    int b = bq * 4 + g;
    bool act = (h < HID);
    const float* yb = y + (size_t)b * T_LEN * HID + h;
    int t0 = c * 256;
    int ts = t0 - 32; if (ts < 0) ts = 0;
    int ng = (t0 + 256 - ts) >> 3;

    float bufA[8], bufB[8], bufC[8];
    auto LD = [&](float* dst, int grp) {
        int gg = grp < ng ? grp : ng - 1;
        int tb = ts + gg * 8;
#pragma unroll
        for (int k = 0; k < 8; ++k)
            dst[k] = act ? yb[(size_t)(tb + k) * HID] : -1.0f;
    };
    LD(bufA, 0); LD(bufB, 1);

    float u = 0.f, o = 0.f;
    for (int gr = 0; gr < ng; ++gr) {
        LD(bufC, gr + 2);
        int tb = ts + gr * 8;
#pragma unroll
        for (int k = 0; k < 8; ++k) {
            float yv = bufA[k];
            u = (o > 0.5f) ? yv : fmaf(0.25f, u, yv);   // 0.25*u exact
            bool sp = (u > 0.2f);
            o = sp ? 1.0f : 0.0f;
            unsigned long long bal = __ballot(sp);
            int t = tb + k;
            if (t >= t0 && h == 0)
                smask[(size_t)b * SM_STRIDE + 128 + t] =
                    (unsigned short)((bal >> (g * 16)) & 0x3FFull);
        }
#pragma unroll
        for (int k = 0; k < 8; ++k) { bufA[k] = bufB[k]; bufB[k] = bufC[k]; }
    }
}

// ---------------------------------------------------------------------------
// K3: LSNN scan + classifier. 64 chunks x 128 live steps, warm 128 (reads the
// zero pad for chunk 0 -> uniform 256-step loop, chunk 0 exact).
// FIVE (b,chunk) units per wave: unit q = lane/12, role r = lane%12
// (r<10 hidden, r=10,11 classifier; lanes 60-63 shadow unit 4, never output).
// One __ballot serves all 5 units; per-unit zmask via per-lane 64-bit shift.
// Tail ids (>=4096) clamp to 4095 for uniform execution but are VALID=false
// and never write (round-3 bug: clamped q-groups also had r==10/11 lanes and
// quadruple-counted (b63,chunk63) -> absmax 352/8192 = 4x88 spikes. Fixed.)
// ---------------------------------------------------------------------------
__global__ __launch_bounds__(64) void k_lsnn(
    const unsigned short* __restrict__ smask,
    const float* __restrict__ w_in, const float* __restrict__ w_rec,
    const float* __restrict__ w_cls, const float* __restrict__ b_cls,
    float* __restrict__ out) {
    __shared__ float T[768];    // [hi?384+m5*12+r]: r<10 -> w_in row r, r>=10 -> w_cls
    int lane = threadIdx.x;
    for (int i = lane; i < 768; i += 64) {
        int r2 = i % 12;
        int m  = (i / 12) & 31;
        int hi = i / (12 * 32);
        const float* wrow = (r2 < HID) ? (w_in + r2 * HID) : (w_cls + (r2 - HID) * HID);
        float s = 0.f;
#pragma unroll
        for (int j = 0; j < 5; ++j)
            if (m & (1u << j)) s += wrow[hi * 5 + j];
        T[i] = s;
    }
    __syncthreads();

    int q = lane / 12;
    int r = lane - q * 12;
    if (q > 4) q = 4;                      // lanes 60-63 shadow unit 4 (r=0..3)
    int shq = q * 12;
    int id = blockIdx.x * 5 + q;
    bool valid = (id < 4096) && (lane < 60);
    if (id > 4095) id = 4095;              // clamp for uniform execution; gated by valid
    int b = id >> 6, chunk = id & 63;

    float wb[HID];
#pragma unroll
    for (int j = 0; j < HID; ++j)
        wb[j] = (r < HID) ? w_rec[r * HID + j] : 0.f;
    float bcl = (r >= HID) ? b_cls[r - HID] : 0.f;

    const unsigned short* sm = smask + (size_t)b * SM_STRIDE + (size_t)chunk * 128;

    auto xlook = [&](const uint4& mv, float* X) {
        unsigned hw[8] = { mv.x & 0x3FFu, (mv.x >> 16) & 0x3FFu,
                           mv.y & 0x3FFu, (mv.y >> 16) & 0x3FFu,
                           mv.z & 0x3FFu, (mv.z >> 16) & 0x3FFu,
                           mv.w & 0x3FFu, (mv.w >> 16) & 0x3FFu };
#pragma unroll
        for (int u = 0; u < 8; ++u)
            X[u] = T[(hw[u] & 31u) * 12 + r] + T[384 + (hw[u] >> 5) * 12 + r];
    };

    uint4 mnext = *(const uint4*)(sm + 8);
    float Xc[8], Xn[8], Pc[8], Pn[8];
    { uint4 m0 = *(const uint4*)(sm); xlook(m0, Xc); }
#pragma unroll
    for (int u = 0; u < 8; ++u) Pc[u] = 0.f;

    float v = 0.f, cur = 0.f;
    unsigned zmask = 0;
    float uc = 0.f, oc = 0.f, accs = 0.f;

    for (int gr = 0; gr < 32; ++gr) {
        int nb = gr + 2; if (nb > 31) nb = 31;
        uint4 mfar = *(const uint4*)(sm + (size_t)nb * 8);
        xlook(mnext, Xn);                  // x_in for next group (off-chain)
#pragma unroll
        for (int u = 0; u < 8; ++u) {
            int zm = (int)zmask;
            float a0 = __int_as_float(__builtin_amdgcn_sbfe(zm, 0, 1) & __float_as_int(wb[0]));
            float a1 = __int_as_float(__builtin_amdgcn_sbfe(zm, 1, 1) & __float_as_int(wb[1]));
            float a2 = __int_as_float(__builtin_amdgcn_sbfe(zm, 2, 1) & __float_as_int(wb[2]));
            float a3 = __int_as_float(__builtin_amdgcn_sbfe(zm, 3, 1) & __float_as_int(wb[3]));
            float a4 = __int_as_float(__builtin_amdgcn_sbfe(zm, 4, 1) & __float_as_int(wb[4]));
            float a5 = __int_as_float(__builtin_amdgcn_sbfe(zm, 5, 1) & __float_as_int(wb[5]));
            float a6 = __int_as_float(__builtin_amdgcn_sbfe(zm, 6, 1) & __float_as_int(wb[6]));
            float a7 = __int_as_float(__builtin_amdgcn_sbfe(zm, 7, 1) & __float_as_int(wb[7]));
            float a8 = __int_as_float(__builtin_amdgcn_sbfe(zm, 8, 1) & __float_as_int(wb[8]));
            float a9 = __int_as_float(__builtin_amdgcn_sbfe(zm, 9, 1) & __float_as_int(wb[9]));
            float s0 = a0 + a1, s1 = a2 + a3, s2 = a4 + a5, s3 = a6 + a7, s4 = a8 + a9;
            float rec = ((s0 + s1) + (s2 + s3)) + s4;

            float ij = (cur + Xc[u]) + rec;
            float vd = v + 0.1f * (ij - v);     // round-1 bit-exact form
            cur = ij - 0.2f * ij;               // round-1 bit-exact form
            bool zb = vd > 0.2f;                // b_dec == VTH exactly
            unsigned long long bal = __ballot(zb);
            v = zb ? 0.f : vd;
            zmask = (unsigned)(bal >> shq) & 0x3FFu;
            Pn[u] = T[(zmask & 31u) * 12 + r] + T[384 + (zmask >> 5) * 12 + r];
        }
        if (gr) {
            bool in = (gr >= 17);              // consuming group gr-1; live from group 16
#pragma unroll
            for (int u = 0; u < 8; ++u) {
                float ci = Pc[u] + bcl;
                uc = (oc > 0.5f) ? ci : fmaf(0.25f, uc, ci);
                oc = (uc > 0.2f) ? 1.f : 0.f;
                if (in) accs += oc;
            }
        }
#pragma unroll
        for (int u = 0; u < 8; ++u) { Xc[u] = Xn[u]; Pc[u] = Pn[u]; }
        mnext = mfar;
    }
    // epilogue: classifier for the last group (always live)
#pragma unroll
    for (int u = 0; u < 8; ++u) {
        float ci = Pc[u] + bcl;
        uc = (oc > 0.5f) ? ci : fmaf(0.25f, uc, ci);
        oc = (uc > 0.2f) ? 1.f : 0.f;
        accs += oc;
    }
    if (valid && (r == 10 || r == 11))
        atomicAdd(&out[b * 2 + (r - 10)], accs * (1.0f / 8192.0f));
}

// ---------------------------------------------------------------------------
extern "C" void kernel_launch(void* const* d_in, const int* in_sizes, int n_in,
                              void* d_out, int out_size, void* d_ws, size_t ws_size,
                              hipStream_t stream) {
    const float* x       = (const float*)d_in[0];
    const float* w_front = (const float*)d_in[1];
    const float* b_front = (const float*)d_in[2];
    const float* w_in    = (const float*)d_in[3];
    const float* w_rec   = (const float*)d_in[4];
    const float* w_cls   = (const float*)d_in[5];
    const float* b_cls   = (const float*)d_in[6];
    float* out = (float*)d_out;

    float* y = (float*)d_ws;                                   // 64*8192*10*4 = 20 MB
    unsigned short* smask =
        (unsigned short*)((char*)d_ws + (size_t)BATCH * T_LEN * HID * sizeof(float));

    hipMemsetAsync(out, 0, (size_t)out_size * sizeof(float), stream);
    hipMemsetAsync(smask, 0, (size_t)BATCH * SM_STRIDE * sizeof(unsigned short), stream);
    k_front<<<dim3(T_LEN / 1024, BATCH), 256, 0, stream>>>(x, w_front, b_front, y);
    k_flif<<<dim3(512), 64, 0, stream>>>(y, smask);
    k_lsnn<<<dim3(820), 64, 0, stream>>>(smask, w_in, w_rec, w_cls, b_cls, out);
}